// Round 14
// baseline (657.244 us; speedup 1.0000x reference)
//
#include <hip/hip_runtime.h>
#include <cmath>

// Multi-scale residual VQ, round 14.
// R13 lesson: s_load and ds_read share lgkmcnt on gfx950 -> hybrid stream
// serializes; argbig reverted to R12's pure-LDS form (proven 552us).
// R14 change: fuse_k was 256 blocks = 1 block/CU = 1 wave/SIMD (latency-
// bound at ~30us vs ~3us compute floor). Split channel groups 4->8:
// grid 512, 4 output channels/block, 4 pixels/thread -> 2 blocks/CU.

#define BB 64
#define CC 32
#define HH 16
#define VV 4096
#define NTOT (BB*CC*HH*HH)   // 524288

__device__ __forceinline__ double cubicw(double x) {
    x = fabs(x);
    const double a = -0.75;
    if (x <= 1.0) return ((a + 2.0) * x - (a + 3.0)) * x * x + 1.0;
    if (x < 2.0)  return (((a * x - 5.0 * a) * x + 8.0 * a) * x - 4.0 * a);
    return 0.0;
}

// monotone float->uint map: d1<d2 (finite) => ordf(d1)<ordf(d2)
__device__ __forceinline__ unsigned int ordf(float d) {
    unsigned int b = __float_as_uint(d);
    return (b & 0x80000000u) ? ~b : (b | 0x80000000u);
}

// init: f_rest=f, f_hat=0, e2 rows, and z for scale 0 (pn=1: per-(b,c) mean).
__global__ void init_k(const float* __restrict__ f, const float* __restrict__ E,
                       float* __restrict__ f_rest, float* __restrict__ f_hat,
                       float* __restrict__ e2, float* __restrict__ z) {
    int i = blockIdx.x * 256 + threadIdx.x;
    if (i < NTOT) { f_rest[i] = f[i]; f_hat[i] = 0.f; }
    if (i < VV) {
        float s = 0.f;
        #pragma unroll
        for (int c = 0; c < CC; ++c) { float e = E[i * CC + c]; s += e * e; }
        e2[i] = s;
    }
    if (i < BB * CC) {
        const float* src = f + (size_t)i * (HH * HH);
        float s = 0.f;
        for (int j = 0; j < HH * HH; ++j) s += src[j];
        z[i] = s * (1.0f / 256.0f);
    }
}

// Small scales: grid (pn*pn, grp); block = 4 waves; each wave = same 64 points
// (one per lane), wave-specific code range (wave-uniform => scalar E loads).
__global__ __launch_bounds__(256, 4) void argsmall_k(const float* __restrict__ z,
        const float* __restrict__ E, const float* __restrict__ e2,
        unsigned long long* __restrict__ bestk, int M, int G, int gsz) {
    const int t = threadIdx.x;
    int m = blockIdx.x * 64 + (t & 63);
    int w = __builtin_amdgcn_readfirstlane(t >> 6);
    int wg = blockIdx.y * 4 + w;
    int v0 = wg * gsz;
    float zr[CC]; float z2 = 0.f;
    const float4* zp = (const float4*)(z + (size_t)m * CC);
    #pragma unroll
    for (int c4 = 0; c4 < 8; ++c4) {
        float4 v = zp[c4];
        zr[c4*4+0] = v.x; zr[c4*4+1] = v.y; zr[c4*4+2] = v.z; zr[c4*4+3] = v.w;
        z2 += v.x*v.x + v.y*v.y + v.z*v.z + v.w*v.w;
    }
    const float* e = E + (size_t)v0 * CC;
    float best = 3.4e38f; int bv = v0;
    for (int v = v0; v < v0 + gsz; v += 2, e += 2 * CC) {
        float a0 = 0.f, a1 = 0.f, b0 = 0.f, b1 = 0.f;
        #pragma unroll
        for (int c = 0; c < CC; c += 2) {
            a0 = fmaf(zr[c],   e[c],      a0);
            a1 = fmaf(zr[c+1], e[c+1],    a1);
            b0 = fmaf(zr[c],   e[CC+c],   b0);
            b1 = fmaf(zr[c+1], e[CC+c+1], b1);
        }
        float dA = fmaf(-2.f, a0 + a1, z2 + e2[v]);
        float dB = fmaf(-2.f, b0 + b1, z2 + e2[v+1]);
        if (dA < best) { best = dA; bv = v; }
        if (dB < best) { best = dB; bv = v + 1; }
    }
    bestk[(size_t)m * G + wg] = ((unsigned long long)ordf(best) << 32) |
                                (unsigned long long)(unsigned int)bv;
}

// Large scales (R12-proven): 2 points/thread; E tile + e2 staged in LDS; inner
// loop reads E via explicit float4 (ds_read_b128 broadcast). Keys [m][G].
__global__ __launch_bounds__(256, 4) void argbig_k(const float* __restrict__ z,
        const float* __restrict__ E, const float* __restrict__ e2,
        unsigned long long* __restrict__ bestk, int M, int G, int gsz) {
    __shared__ float s_e[128 * CC];   // up to 128 codes x 32 ch = 16 KB
    __shared__ float s_e2[128];
    const int T = gridDim.x * 256;
    const int g = blockIdx.y;
    const int v0 = g * gsz;
    {
        const float4* src = (const float4*)(E + (size_t)v0 * CC);
        float4* dst = (float4*)s_e;
        for (int i = threadIdx.x; i < gsz * 8; i += 256) dst[i] = src[i];
        if (threadIdx.x < gsz) s_e2[threadIdx.x] = e2[v0 + threadIdx.x];
    }
    int   mm[2];
    bool  act[2];
    float zr[2][CC];
    float z2[2];
    #pragma unroll
    for (int pt = 0; pt < 2; ++pt) {
        int m0 = blockIdx.x * 256 + threadIdx.x + pt * T;
        act[pt] = (m0 < M);
        int m = act[pt] ? m0 : M - 1;
        mm[pt] = m;
        const float4* zp = (const float4*)(z + (size_t)m * CC);
        float zz = 0.f;
        #pragma unroll
        for (int c4 = 0; c4 < 8; ++c4) {
            float4 v = zp[c4];
            zr[pt][c4*4+0] = v.x; zr[pt][c4*4+1] = v.y;
            zr[pt][c4*4+2] = v.z; zr[pt][c4*4+3] = v.w;
            zz += v.x*v.x + v.y*v.y + v.z*v.z + v.w*v.w;
        }
        z2[pt] = zz;
    }
    __syncthreads();
    float best[2]; int bv[2];
    #pragma unroll
    for (int pt = 0; pt < 2; ++pt) { best[pt] = 3.4e38f; bv[pt] = v0; }
    const float4* ev = (const float4*)s_e;
    for (int vi = 0; vi < gsz; ++vi, ev += 8) {
        float4 e0 = ev[0], e1 = ev[1], e2v = ev[2], e3 = ev[3];
        float4 e4 = ev[4], e5 = ev[5], e6v = ev[6], e7 = ev[7];
        float ef[CC] = {e0.x,e0.y,e0.z,e0.w, e1.x,e1.y,e1.z,e1.w,
                        e2v.x,e2v.y,e2v.z,e2v.w, e3.x,e3.y,e3.z,e3.w,
                        e4.x,e4.y,e4.z,e4.w, e5.x,e5.y,e5.z,e5.w,
                        e6v.x,e6v.y,e6v.z,e6v.w, e7.x,e7.y,e7.z,e7.w};
        float a0 = 0.f, a1 = 0.f, b0 = 0.f, b1 = 0.f;
        #pragma unroll
        for (int c = 0; c < CC; c += 2) {
            a0 = fmaf(zr[0][c],   ef[c],   a0);
            a1 = fmaf(zr[0][c+1], ef[c+1], a1);
            b0 = fmaf(zr[1][c],   ef[c],   b0);
            b1 = fmaf(zr[1][c+1], ef[c+1], b1);
        }
        float e2c = s_e2[vi];
        float dA = fmaf(-2.f, a0 + a1, z2[0] + e2c);
        float dB = fmaf(-2.f, b0 + b1, z2[1] + e2c);
        int v = v0 + vi;
        if (dA < best[0]) { best[0] = dA; bv[0] = v; }
        if (dB < best[1]) { best[1] = dB; bv[1] = v; }
    }
    #pragma unroll
    for (int pt = 0; pt < 2; ++pt)
        if (act[pt])
            bestk[(size_t)mm[pt] * G + g] =
                ((unsigned long long)ordf(best[pt]) << 32) |
                (unsigned long long)(unsigned int)bv[pt];
}

// Fused: group-reduce keys -> gather + separable bicubic (all 32 ch, LDS) ->
// 3x3 conv Phi for THIS BLOCK'S 4 output channels -> f_hat/f_rest update ->
// emit next scale's z rows (4 channels). grid (8, 64) = 512 blocks, 2/CU.
__global__ __launch_bounds__(256) void fuse_k(const unsigned long long* __restrict__ bestk,
                      const float* __restrict__ E,
                      const float* __restrict__ pw, const float* __restrict__ pb,
                      float* __restrict__ f_hat, float* __restrict__ f_rest,
                      float* __restrict__ z_next,
                      int pn, int G, int TPP, int kphi, int pnn) {
    __shared__ float s_buf[CC * 18 * 20];
    __shared__ float s_pw[CC * 9 * 4];      // transposed: [ci*9+tap][col], 4 cols
    __shared__ int   s_idx[256];
    __shared__ float s_w[HH][4];
    __shared__ int   s_j[HH][4];
    __shared__ unsigned long long s_red[256];
    const int t   = threadIdx.x;
    const int cog = blockIdx.x;   // 0..7 (4 output channels each)
    const int b   = blockIdx.y;   // 0..63
    const int P   = pn * pn;

    // ---- phase 0: reduce over G keys per point (min d, tie -> min v) ----
    if (TPP == 1) {
        if (t < P) {
            int m = b * P + t;
            const ulonglong2* kp = (const ulonglong2*)(bestk + (size_t)m * G);
            unsigned long long bk = ~0ull;
            #pragma unroll 4
            for (int gg = 0; gg < (G >> 1); ++gg) {
                ulonglong2 o = kp[gg];
                unsigned long long mn = o.x < o.y ? o.x : o.y;
                if (mn < bk) bk = mn;
            }
            s_idx[t] = (int)(unsigned int)(bk & 0xffffffffull);
        }
    } else {
        int p = t / TPP, sub = t - p * TPP;
        unsigned long long bk = ~0ull;
        if (p < P) {
            const unsigned long long* kp = bestk + (size_t)(b * P + p) * G;
            for (int gg = sub; gg < G; gg += TPP) {
                unsigned long long o = kp[gg];
                if (o < bk) bk = o;
            }
        }
        s_red[t] = bk;
        __syncthreads();
        for (int s = TPP >> 1; s > 0; s >>= 1) {
            if (sub < s && p < P) {
                unsigned long long o = s_red[t + s];
                if (o < s_red[t]) s_red[t] = o;
            }
            __syncthreads();
        }
        if (t < P) s_idx[t] = (int)(unsigned int)(s_red[t * TPP] & 0xffffffffull);
    }
    if (t < HH) {
        double src = (t + 0.5) * (double)pn / 16.0 - 0.5;
        double fi = floor(src); int i0 = (int)fi; double tt = src - fi;
        #pragma unroll
        for (int k = 0; k < 4; ++k) {
            int j = i0 - 1 + k; j = j < 0 ? 0 : (j > pn - 1 ? pn - 1 : j);
            s_j[t][k] = j;
            s_w[t][k] = (float)cubicw((double)(k - 1) - tt);
        }
    }
    {
        // transposed staging: s_pw[(ci*9+tap)*4 + col] for this block's 4 cols
        const float* src = pw + ((size_t)(kphi * CC + cog * 4)) * CC * 9;
        for (int i = t; i < 4 * CC * 9; i += 256) {
            int cl = i / (CC * 9);
            int r  = i - cl * (CC * 9);       // ci*9 + tap
            s_pw[r * 4 + cl] = src[i];
        }
    }
    __syncthreads();

    // ---- phase A: vertical bicubic + gather: tmp[c][h][q] (all 32 ch) ----
    if (t < HH * pn) {
        int h = t / pn, q = t % pn;
        float acc[CC];
        #pragma unroll
        for (int c = 0; c < CC; ++c) acc[c] = 0.f;
        #pragma unroll
        for (int k = 0; k < 4; ++k) {
            float wv = s_w[h][k];
            int row = s_idx[s_j[h][k] * pn + q];
            const float4* er = (const float4*)(E + (size_t)row * CC);
            #pragma unroll
            for (int c4 = 0; c4 < CC / 4; ++c4) {
                float4 e4 = er[c4];
                acc[c4*4+0] = fmaf(wv, e4.x, acc[c4*4+0]);
                acc[c4*4+1] = fmaf(wv, e4.y, acc[c4*4+1]);
                acc[c4*4+2] = fmaf(wv, e4.z, acc[c4*4+2]);
                acc[c4*4+3] = fmaf(wv, e4.w, acc[c4*4+3]);
            }
        }
        #pragma unroll
        for (int c = 0; c < CC; ++c) s_buf[(c * HH + h) * pn + q] = acc[c];
    }
    __syncthreads();

    // ---- phase B: horizontal bicubic -> padded hup[c][18][20] ----
    {
        int h = t >> 4, w = t & 15;
        float acc[CC];
        #pragma unroll
        for (int c = 0; c < CC; ++c) acc[c] = 0.f;
        #pragma unroll
        for (int k = 0; k < 4; ++k) {
            float wh = s_w[w][k];
            int j = s_j[w][k];
            #pragma unroll
            for (int c = 0; c < CC; ++c)
                acc[c] = fmaf(wh, s_buf[(c * HH + h) * pn + j], acc[c]);
        }
        __syncthreads();
        #pragma unroll
        for (int c = 0; c < CC; ++c) s_buf[(c * 18 + h + 1) * 20 + w + 1] = acc[c];
        if (w == 0) {
            #pragma unroll
            for (int c = 0; c < CC; ++c) s_buf[(c * 18 + h + 1) * 20] = 0.f;
        }
        if (w >= 13) {
            #pragma unroll
            for (int c = 0; c < CC; ++c) s_buf[(c * 18 + h + 1) * 20 + w + 4] = 0.f;
        }
        if (h == 0) {
            #pragma unroll
            for (int c = 0; c < CC; ++c) {
                s_buf[(c * 18) * 20 + w] = 0.f;
                if (w < 4) s_buf[(c * 18) * 20 + 16 + w] = 0.f;
            }
        }
        if (h == 15) {
            #pragma unroll
            for (int c = 0; c < CC; ++c) {
                s_buf[(c * 18 + 17) * 20 + w] = 0.f;
                if (w < 4) s_buf[(c * 18 + 17) * 20 + 16 + w] = 0.f;
            }
        }
    }
    __syncthreads();

    // ---- conv 3x3: thread -> (col, h, w0..w0+3); col wave-uniform ----
    int col = t >> 6;                 // 0..3 (uniform per wave)
    int co  = cog * 4 + col;
    int s   = t & 63;
    int h   = s >> 2;                 // 0..15
    int w0  = (s & 3) * 4;            // 0,4,8,12
    float acc[4];
    float bias = pb[kphi * CC + co];
    #pragma unroll
    for (int o = 0; o < 4; ++o) acc[o] = bias;
    for (int ci = 0; ci < CC; ++ci) {
        const float* wb = &s_pw[(ci * 9) * 4 + col];
        #pragma unroll
        for (int kh = 0; kh < 3; ++kh) {
            const float4* xr = (const float4*)&s_buf[(ci * 18 + h + kh) * 20 + w0];
            float4 a0 = xr[0], a1 = xr[1];
            float xf[8] = {a0.x, a0.y, a0.z, a0.w, a1.x, a1.y, a1.z, a1.w};
            float k0 = wb[(kh*3+0)*4], k1 = wb[(kh*3+1)*4], k2 = wb[(kh*3+2)*4];
            #pragma unroll
            for (int o = 0; o < 4; ++o)
                acc[o] += xf[o] * k0 + xf[o+1] * k1 + xf[o+2] * k2;
        }
    }
    // ---- epilogue: update f_hat / f_rest (one float4 each) ----
    size_t base = ((size_t)(b * CC + co) * HH + h) * HH + w0;
    float hf[4];
    #pragma unroll
    for (int o = 0; o < 4; ++o) {
        float hv = s_buf[(co * 18 + h + 1) * 20 + w0 + o + 1];
        hf[o] = 0.5f * hv + 0.5f * acc[o];
    }
    float4* fh = (float4*)(f_hat + base);
    float4* fr = (float4*)(f_rest + base);
    float4 v0 = fh[0];
    v0.x += hf[0]; v0.y += hf[1]; v0.z += hf[2]; v0.w += hf[3];
    fh[0] = v0;
    float4 r0 = fr[0];
    r0.x -= hf[0]; r0.y -= hf[1]; r0.z -= hf[2]; r0.w -= hf[3];
    fr[0] = r0;

    // ---- emit next scale's z rows for this block's 4 channels ----
    if (pnn > 0) {
        __syncthreads();   // all s_buf reads (hv/conv) complete
        float* fn = s_buf; // reuse: fnew[col][16][16]
        float* d = &fn[(col * HH + h) * HH + w0];
        d[0] = r0.x; d[1] = r0.y; d[2] = r0.z; d[3] = r0.w;
        __syncthreads();
        int P2 = pnn * pnn;
        for (int i = t; i < P2 * 4; i += 256) {
            int cl = i & 3, pq = i >> 2;
            int q2 = pq % pnn, p2 = pq / pnn;
            int sp = (p2 * HH) / pnn, ep = ((p2 + 1) * HH + pnn - 1) / pnn;
            int sq = (q2 * HH) / pnn, eq = ((q2 + 1) * HH + pnn - 1) / pnn;
            float wgt = 1.0f / ((float)(ep - sp) * (float)(eq - sq));
            float sum = 0.f;
            for (int h2 = sp; h2 < ep; ++h2)
                for (int w2 = sq; w2 < eq; ++w2)
                    sum += fn[(cl * HH + h2) * HH + w2];
            z_next[((size_t)(b * P2 + pq)) * CC + cog * 4 + cl] = sum * wgt;
        }
    }
}

extern "C" void kernel_launch(void* const* d_in, const int* in_sizes, int n_in,
                              void* d_out, int out_size, void* d_ws, size_t ws_size,
                              hipStream_t stream) {
    const float* f  = (const float*)d_in[0];
    const float* E  = (const float*)d_in[1];
    const float* pw = (const float*)d_in[2];
    const float* pb = (const float*)d_in[3];
    float* out = (float*)d_out;

    float* wsf    = (float*)d_ws;
    float* f_rest = wsf;
    float* e2     = wsf + (size_t)NTOT;
    unsigned long long* bestk = (unsigned long long*)(e2 + VV);  // 524288 u64
    float* z      = (float*)(bestk + 524288);

    int phik[10];
    {
        double start = 1.0 / 3.0 / 4.0;
        double stop  = 1.0 - 1.0 / 3.0 / 4.0;
        double step  = (stop - start) / 3.0;
        double ticks[4];
        for (int i = 0; i < 4; ++i) ticks[i] = (double)i * step + start;
        ticks[3] = stop;
        for (int si = 0; si < 10; ++si) {
            double s = (double)si / 9.0;
            int bk = 0; double bd = fabs(ticks[0] - s);
            for (int tq = 1; tq < 4; ++tq) {
                double d2 = fabs(ticks[tq] - s);
                if (d2 < bd) { bd = d2; bk = tq; }
            }
            phik[si] = bk;
        }
    }

    static const int pns[10]  = {1, 2, 3, 4, 5, 6, 8, 10, 13, 16};
    static const int grpS[10] = {256, 128, 64, 32, 32, 16, 0, 0, 0, 0};
    // big scales (R12-proven): G key-rows, gsz = VV/G <= 128 (LDS tile)
    static const int grpB[10] = {0, 0, 0, 0, 0, 0, 64, 64, 32, 32};

    init_k<<<(NTOT + 255) / 256, 256, 0, stream>>>(f, E, f_rest, out, e2, z);

    for (int si = 0; si < 10; ++si) {
        int pn = pns[si];
        int P = pn * pn;
        int M = BB * P;
        int G, TPP;
        if (pn <= 6) {
            int grp = grpS[si];
            G = grp * 4;
            int gsz = VV / G;
            argsmall_k<<<dim3(P, grp), 256, 0, stream>>>(z, E, e2, bestk, M, G, gsz);
        } else {
            G = grpB[si];
            int gsz = VV / G;
            int bx = (M + 511) / 512;
            dim3 ag(bx, G);
            argbig_k<<<ag, 256, 0, stream>>>(z, E, e2, bestk, M, G, gsz);
        }
        TPP = 1;
        while (TPP * 2 * P <= 256) TPP *= 2;
        int pnn = (si < 9) ? pns[si + 1] : 0;
        fuse_k<<<dim3(8, BB), 256, 0, stream>>>(bestk, E, pw, pb,
                                                out, f_rest, z,
                                                pn, G, TPP, phik[si], pnn);
    }
}

// Round 15
// 557.629 us; speedup vs baseline: 1.1786x; 1.1786x over previous
//
#include <hip/hip_runtime.h>
#include <cmath>

// Multi-scale residual VQ, round 15 = R12 (proven 552us) + pn8 G=64->128.
// R13/R14 lessons: hybrid K$+LDS streams share lgkmcnt (serialize); fuse_k
// is DS-throughput-bound, so co-splitting (+33% DS, duplicated phases) lost.
// This revision is R12 byte-identical except grpB[pn8]=128 (traffic-neutral,
// 1024 blocks = 4/CU like pn16's proven point; keys 4096*128 = 524288 fits).

#define BB 64
#define CC 32
#define HH 16
#define VV 4096
#define NTOT (BB*CC*HH*HH)   // 524288

__device__ __forceinline__ double cubicw(double x) {
    x = fabs(x);
    const double a = -0.75;
    if (x <= 1.0) return ((a + 2.0) * x - (a + 3.0)) * x * x + 1.0;
    if (x < 2.0)  return (((a * x - 5.0 * a) * x + 8.0 * a) * x - 4.0 * a);
    return 0.0;
}

// monotone float->uint map: d1<d2 (finite) => ordf(d1)<ordf(d2)
__device__ __forceinline__ unsigned int ordf(float d) {
    unsigned int b = __float_as_uint(d);
    return (b & 0x80000000u) ? ~b : (b | 0x80000000u);
}

// init: f_rest=f, f_hat=0, e2 rows, and z for scale 0 (pn=1: per-(b,c) mean).
__global__ void init_k(const float* __restrict__ f, const float* __restrict__ E,
                       float* __restrict__ f_rest, float* __restrict__ f_hat,
                       float* __restrict__ e2, float* __restrict__ z) {
    int i = blockIdx.x * 256 + threadIdx.x;
    if (i < NTOT) { f_rest[i] = f[i]; f_hat[i] = 0.f; }
    if (i < VV) {
        float s = 0.f;
        #pragma unroll
        for (int c = 0; c < CC; ++c) { float e = E[i * CC + c]; s += e * e; }
        e2[i] = s;
    }
    if (i < BB * CC) {
        const float* src = f + (size_t)i * (HH * HH);
        float s = 0.f;
        for (int j = 0; j < HH * HH; ++j) s += src[j];
        z[i] = s * (1.0f / 256.0f);
    }
}

// Small scales: grid (pn*pn, grp); block = 4 waves; each wave = same 64 points
// (one per lane), wave-specific code range (wave-uniform => scalar E loads).
__global__ __launch_bounds__(256, 4) void argsmall_k(const float* __restrict__ z,
        const float* __restrict__ E, const float* __restrict__ e2,
        unsigned long long* __restrict__ bestk, int M, int G, int gsz) {
    const int t = threadIdx.x;
    int m = blockIdx.x * 64 + (t & 63);
    int w = __builtin_amdgcn_readfirstlane(t >> 6);
    int wg = blockIdx.y * 4 + w;
    int v0 = wg * gsz;
    float zr[CC]; float z2 = 0.f;
    const float4* zp = (const float4*)(z + (size_t)m * CC);
    #pragma unroll
    for (int c4 = 0; c4 < 8; ++c4) {
        float4 v = zp[c4];
        zr[c4*4+0] = v.x; zr[c4*4+1] = v.y; zr[c4*4+2] = v.z; zr[c4*4+3] = v.w;
        z2 += v.x*v.x + v.y*v.y + v.z*v.z + v.w*v.w;
    }
    const float* e = E + (size_t)v0 * CC;
    float best = 3.4e38f; int bv = v0;
    for (int v = v0; v < v0 + gsz; v += 2, e += 2 * CC) {
        float a0 = 0.f, a1 = 0.f, b0 = 0.f, b1 = 0.f;
        #pragma unroll
        for (int c = 0; c < CC; c += 2) {
            a0 = fmaf(zr[c],   e[c],      a0);
            a1 = fmaf(zr[c+1], e[c+1],    a1);
            b0 = fmaf(zr[c],   e[CC+c],   b0);
            b1 = fmaf(zr[c+1], e[CC+c+1], b1);
        }
        float dA = fmaf(-2.f, a0 + a1, z2 + e2[v]);
        float dB = fmaf(-2.f, b0 + b1, z2 + e2[v+1]);
        if (dA < best) { best = dA; bv = v; }
        if (dB < best) { best = dB; bv = v + 1; }
    }
    bestk[(size_t)m * G + wg] = ((unsigned long long)ordf(best) << 32) |
                                (unsigned long long)(unsigned int)bv;
}

// Large scales (R12-proven): 2 points/thread; E tile + e2 staged in LDS; inner
// loop reads E via explicit float4 (ds_read_b128 broadcast). Keys [m][G].
__global__ __launch_bounds__(256, 4) void argbig_k(const float* __restrict__ z,
        const float* __restrict__ E, const float* __restrict__ e2,
        unsigned long long* __restrict__ bestk, int M, int G, int gsz) {
    __shared__ float s_e[128 * CC];   // up to 128 codes x 32 ch = 16 KB
    __shared__ float s_e2[128];
    const int T = gridDim.x * 256;
    const int g = blockIdx.y;
    const int v0 = g * gsz;
    {
        const float4* src = (const float4*)(E + (size_t)v0 * CC);
        float4* dst = (float4*)s_e;
        for (int i = threadIdx.x; i < gsz * 8; i += 256) dst[i] = src[i];
        if (threadIdx.x < gsz) s_e2[threadIdx.x] = e2[v0 + threadIdx.x];
    }
    int   mm[2];
    bool  act[2];
    float zr[2][CC];
    float z2[2];
    #pragma unroll
    for (int pt = 0; pt < 2; ++pt) {
        int m0 = blockIdx.x * 256 + threadIdx.x + pt * T;
        act[pt] = (m0 < M);
        int m = act[pt] ? m0 : M - 1;
        mm[pt] = m;
        const float4* zp = (const float4*)(z + (size_t)m * CC);
        float zz = 0.f;
        #pragma unroll
        for (int c4 = 0; c4 < 8; ++c4) {
            float4 v = zp[c4];
            zr[pt][c4*4+0] = v.x; zr[pt][c4*4+1] = v.y;
            zr[pt][c4*4+2] = v.z; zr[pt][c4*4+3] = v.w;
            zz += v.x*v.x + v.y*v.y + v.z*v.z + v.w*v.w;
        }
        z2[pt] = zz;
    }
    __syncthreads();
    float best[2]; int bv[2];
    #pragma unroll
    for (int pt = 0; pt < 2; ++pt) { best[pt] = 3.4e38f; bv[pt] = v0; }
    const float4* ev = (const float4*)s_e;
    for (int vi = 0; vi < gsz; ++vi, ev += 8) {
        float4 e0 = ev[0], e1 = ev[1], e2v = ev[2], e3 = ev[3];
        float4 e4 = ev[4], e5 = ev[5], e6v = ev[6], e7 = ev[7];
        float ef[CC] = {e0.x,e0.y,e0.z,e0.w, e1.x,e1.y,e1.z,e1.w,
                        e2v.x,e2v.y,e2v.z,e2v.w, e3.x,e3.y,e3.z,e3.w,
                        e4.x,e4.y,e4.z,e4.w, e5.x,e5.y,e5.z,e5.w,
                        e6v.x,e6v.y,e6v.z,e6v.w, e7.x,e7.y,e7.z,e7.w};
        float a0 = 0.f, a1 = 0.f, b0 = 0.f, b1 = 0.f;
        #pragma unroll
        for (int c = 0; c < CC; c += 2) {
            a0 = fmaf(zr[0][c],   ef[c],   a0);
            a1 = fmaf(zr[0][c+1], ef[c+1], a1);
            b0 = fmaf(zr[1][c],   ef[c],   b0);
            b1 = fmaf(zr[1][c+1], ef[c+1], b1);
        }
        float e2c = s_e2[vi];
        float dA = fmaf(-2.f, a0 + a1, z2[0] + e2c);
        float dB = fmaf(-2.f, b0 + b1, z2[1] + e2c);
        int v = v0 + vi;
        if (dA < best[0]) { best[0] = dA; bv[0] = v; }
        if (dB < best[1]) { best[1] = dB; bv[1] = v; }
    }
    #pragma unroll
    for (int pt = 0; pt < 2; ++pt)
        if (act[pt])
            bestk[(size_t)mm[pt] * G + g] =
                ((unsigned long long)ordf(best[pt]) << 32) |
                (unsigned long long)(unsigned int)bv[pt];
}

// Fused: group-reduce keys ([m][G], vectorized when TPP==1) -> gather +
// separable bicubic (LDS, padded) -> 3x3 conv Phi (transposed conflict-free
// weights) -> f_hat/f_rest update -> emit next scale's z rows.
__global__ __launch_bounds__(256) void fuse_k(const unsigned long long* __restrict__ bestk,
                      const float* __restrict__ E,
                      const float* __restrict__ pw, const float* __restrict__ pb,
                      float* __restrict__ f_hat, float* __restrict__ f_rest,
                      float* __restrict__ z_next,
                      int pn, int G, int TPP, int kphi, int pnn) {
    __shared__ float s_buf[CC * 18 * 20];
    __shared__ float s_pw[CC * 9 * 8];      // transposed: [ci*9+tap][col]
    __shared__ int   s_idx[256];
    __shared__ float s_w[HH][4];
    __shared__ int   s_j[HH][4];
    __shared__ unsigned long long s_red[256];
    const int t   = threadIdx.x;
    const int cog = blockIdx.x;
    const int b   = blockIdx.y;
    const int P   = pn * pn;

    if (TPP == 1) {
        if (t < P) {
            int m = b * P + t;
            const ulonglong2* kp = (const ulonglong2*)(bestk + (size_t)m * G);
            unsigned long long bk = ~0ull;
            #pragma unroll 4
            for (int gg = 0; gg < (G >> 1); ++gg) {
                ulonglong2 o = kp[gg];
                unsigned long long mn = o.x < o.y ? o.x : o.y;
                if (mn < bk) bk = mn;
            }
            s_idx[t] = (int)(unsigned int)(bk & 0xffffffffull);
        }
    } else {
        int p = t / TPP, sub = t - p * TPP;
        unsigned long long bk = ~0ull;
        if (p < P) {
            const unsigned long long* kp = bestk + (size_t)(b * P + p) * G;
            for (int gg = sub; gg < G; gg += TPP) {
                unsigned long long o = kp[gg];
                if (o < bk) bk = o;
            }
        }
        s_red[t] = bk;
        __syncthreads();
        for (int s = TPP >> 1; s > 0; s >>= 1) {
            if (sub < s && p < P) {
                unsigned long long o = s_red[t + s];
                if (o < s_red[t]) s_red[t] = o;
            }
            __syncthreads();
        }
        if (t < P) s_idx[t] = (int)(unsigned int)(s_red[t * TPP] & 0xffffffffull);
    }
    if (t < HH) {
        double src = (t + 0.5) * (double)pn / 16.0 - 0.5;
        double fi = floor(src); int i0 = (int)fi; double tt = src - fi;
        #pragma unroll
        for (int k = 0; k < 4; ++k) {
            int j = i0 - 1 + k; j = j < 0 ? 0 : (j > pn - 1 ? pn - 1 : j);
            s_j[t][k] = j;
            s_w[t][k] = (float)cubicw((double)(k - 1) - tt);
        }
    }
    {
        const float* src = pw + ((size_t)(kphi * CC + cog * 8)) * CC * 9;
        for (int i = t; i < 8 * CC * 9; i += 256) {
            int col = i / (CC * 9);
            int r   = i - col * (CC * 9);
            s_pw[r * 8 + col] = src[i];
        }
    }
    __syncthreads();

    if (t < HH * pn) {
        int h = t / pn, q = t % pn;
        float acc[CC];
        #pragma unroll
        for (int c = 0; c < CC; ++c) acc[c] = 0.f;
        #pragma unroll
        for (int k = 0; k < 4; ++k) {
            float wv = s_w[h][k];
            int row = s_idx[s_j[h][k] * pn + q];
            const float4* er = (const float4*)(E + (size_t)row * CC);
            #pragma unroll
            for (int c4 = 0; c4 < CC / 4; ++c4) {
                float4 e4 = er[c4];
                acc[c4*4+0] = fmaf(wv, e4.x, acc[c4*4+0]);
                acc[c4*4+1] = fmaf(wv, e4.y, acc[c4*4+1]);
                acc[c4*4+2] = fmaf(wv, e4.z, acc[c4*4+2]);
                acc[c4*4+3] = fmaf(wv, e4.w, acc[c4*4+3]);
            }
        }
        #pragma unroll
        for (int c = 0; c < CC; ++c) s_buf[(c * HH + h) * pn + q] = acc[c];
    }
    __syncthreads();

    {
        int h = t >> 4, w = t & 15;
        float acc[CC];
        #pragma unroll
        for (int c = 0; c < CC; ++c) acc[c] = 0.f;
        #pragma unroll
        for (int k = 0; k < 4; ++k) {
            float wh = s_w[w][k];
            int j = s_j[w][k];
            #pragma unroll
            for (int c = 0; c < CC; ++c)
                acc[c] = fmaf(wh, s_buf[(c * HH + h) * pn + j], acc[c]);
        }
        __syncthreads();
        #pragma unroll
        for (int c = 0; c < CC; ++c) s_buf[(c * 18 + h + 1) * 20 + w + 1] = acc[c];
        if (w == 0) {
            #pragma unroll
            for (int c = 0; c < CC; ++c) s_buf[(c * 18 + h + 1) * 20] = 0.f;
        }
        if (w >= 13) {
            #pragma unroll
            for (int c = 0; c < CC; ++c) s_buf[(c * 18 + h + 1) * 20 + w + 4] = 0.f;
        }
        if (h == 0) {
            #pragma unroll
            for (int c = 0; c < CC; ++c) {
                s_buf[(c * 18) * 20 + w] = 0.f;
                if (w < 4) s_buf[(c * 18) * 20 + 16 + w] = 0.f;
            }
        }
        if (h == 15) {
            #pragma unroll
            for (int c = 0; c < CC; ++c) {
                s_buf[(c * 18 + 17) * 20 + w] = 0.f;
                if (w < 4) s_buf[(c * 18 + 17) * 20 + 16 + w] = 0.f;
            }
        }
    }
    __syncthreads();

    int col = t >> 5;
    int co  = cog * 8 + col;
    int s   = t & 31;
    int h   = s >> 1;
    int w0  = (s & 1) * 8;
    float acc[8];
    float bias = pb[kphi * CC + co];
    #pragma unroll
    for (int o = 0; o < 8; ++o) acc[o] = bias;
    for (int ci = 0; ci < CC; ++ci) {
        const float* wb = &s_pw[(ci * 9) * 8 + col];
        #pragma unroll
        for (int kh = 0; kh < 3; ++kh) {
            const float4* xr = (const float4*)&s_buf[(ci * 18 + h + kh) * 20 + w0];
            float4 a0 = xr[0], a1 = xr[1], a2 = xr[2];
            float xf[12] = {a0.x, a0.y, a0.z, a0.w, a1.x, a1.y, a1.z, a1.w,
                            a2.x, a2.y, a2.z, a2.w};
            float k0 = wb[(kh*3+0)*8], k1 = wb[(kh*3+1)*8], k2 = wb[(kh*3+2)*8];
            #pragma unroll
            for (int o = 0; o < 8; ++o)
                acc[o] += xf[o] * k0 + xf[o+1] * k1 + xf[o+2] * k2;
        }
    }
    size_t base = ((size_t)(b * CC + co) * HH + h) * HH + w0;
    float hf[8];
    #pragma unroll
    for (int o = 0; o < 8; ++o) {
        float hv = s_buf[(co * 18 + h + 1) * 20 + w0 + o + 1];
        hf[o] = 0.5f * hv + 0.5f * acc[o];
    }
    float4* fh = (float4*)(f_hat + base);
    float4* fr = (float4*)(f_rest + base);
    float4 v0 = fh[0], v1 = fh[1];
    v0.x += hf[0]; v0.y += hf[1]; v0.z += hf[2]; v0.w += hf[3];
    v1.x += hf[4]; v1.y += hf[5]; v1.z += hf[6]; v1.w += hf[7];
    fh[0] = v0; fh[1] = v1;
    float4 r0 = fr[0], r1 = fr[1];
    r0.x -= hf[0]; r0.y -= hf[1]; r0.z -= hf[2]; r0.w -= hf[3];
    r1.x -= hf[4]; r1.y -= hf[5]; r1.z -= hf[6]; r1.w -= hf[7];
    fr[0] = r0; fr[1] = r1;

    if (pnn > 0) {
        __syncthreads();
        float* fn = s_buf;
        float* d = &fn[(col * HH + h) * HH + w0];
        d[0] = r0.x; d[1] = r0.y; d[2] = r0.z; d[3] = r0.w;
        d[4] = r1.x; d[5] = r1.y; d[6] = r1.z; d[7] = r1.w;
        __syncthreads();
        int P2 = pnn * pnn;
        for (int i = t; i < P2 * 8; i += 256) {
            int cl = i & 7, pq = i >> 3;
            int q2 = pq % pnn, p2 = pq / pnn;
            int sp = (p2 * HH) / pnn, ep = ((p2 + 1) * HH + pnn - 1) / pnn;
            int sq = (q2 * HH) / pnn, eq = ((q2 + 1) * HH + pnn - 1) / pnn;
            float wgt = 1.0f / ((float)(ep - sp) * (float)(eq - sq));
            float sum = 0.f;
            for (int h2 = sp; h2 < ep; ++h2)
                for (int w2 = sq; w2 < eq; ++w2)
                    sum += fn[(cl * HH + h2) * HH + w2];
            z_next[((size_t)(b * P2 + pq)) * CC + cog * 8 + cl] = sum * wgt;
        }
    }
}

extern "C" void kernel_launch(void* const* d_in, const int* in_sizes, int n_in,
                              void* d_out, int out_size, void* d_ws, size_t ws_size,
                              hipStream_t stream) {
    const float* f  = (const float*)d_in[0];
    const float* E  = (const float*)d_in[1];
    const float* pw = (const float*)d_in[2];
    const float* pb = (const float*)d_in[3];
    float* out = (float*)d_out;

    float* wsf    = (float*)d_ws;
    float* f_rest = wsf;
    float* e2     = wsf + (size_t)NTOT;
    unsigned long long* bestk = (unsigned long long*)(e2 + VV);  // 524288 u64
    float* z      = (float*)(bestk + 524288);

    int phik[10];
    {
        double start = 1.0 / 3.0 / 4.0;
        double stop  = 1.0 - 1.0 / 3.0 / 4.0;
        double step  = (stop - start) / 3.0;
        double ticks[4];
        for (int i = 0; i < 4; ++i) ticks[i] = (double)i * step + start;
        ticks[3] = stop;
        for (int si = 0; si < 10; ++si) {
            double s = (double)si / 9.0;
            int bk = 0; double bd = fabs(ticks[0] - s);
            for (int tq = 1; tq < 4; ++tq) {
                double d2 = fabs(ticks[tq] - s);
                if (d2 < bd) { bd = d2; bk = tq; }
            }
            phik[si] = bk;
        }
    }

    static const int pns[10]  = {1, 2, 3, 4, 5, 6, 8, 10, 13, 16};
    static const int grpS[10] = {256, 128, 64, 32, 32, 16, 0, 0, 0, 0};
    // big scales: G key-rows (keys M*G <= 524288), gsz = VV/G <= 128 (LDS tile)
    // pn8: G=128 -> 1024 blocks = 4/CU (pn16's proven occupancy point).
    static const int grpB[10] = {0, 0, 0, 0, 0, 0, 128, 64, 32, 32};

    init_k<<<(NTOT + 255) / 256, 256, 0, stream>>>(f, E, f_rest, out, e2, z);

    for (int si = 0; si < 10; ++si) {
        int pn = pns[si];
        int P = pn * pn;
        int M = BB * P;
        int G, TPP;
        if (pn <= 6) {
            int grp = grpS[si];
            G = grp * 4;
            int gsz = VV / G;
            argsmall_k<<<dim3(P, grp), 256, 0, stream>>>(z, E, e2, bestk, M, G, gsz);
        } else {
            G = grpB[si];
            int gsz = VV / G;
            int bx = (M + 511) / 512;
            dim3 ag(bx, G);
            argbig_k<<<ag, 256, 0, stream>>>(z, E, e2, bestk, M, G, gsz);
        }
        TPP = 1;
        while (TPP * 2 * P <= 256) TPP *= 2;
        int pnn = (si < 9) ? pns[si + 1] : 0;
        fuse_k<<<dim3(4, BB), 256, 0, stream>>>(bestk, E, pw, pb,
                                                out, f_rest, z,
                                                pn, G, TPP, phik[si], pnn);
    }
}

// Round 16
// 518.428 us; speedup vs baseline: 1.2678x; 1.0756x over previous
//
#include <hip/hip_runtime.h>
#include <cmath>

// Multi-scale residual VQ, round 16 = R15 argmin path + 512-thread fuse_k.
// R14 lesson: buying fuse occupancy by duplicating traffic loses. R16 buys
// waves traffic-free: one 512-thread block per (cog,b) (8 waves = 2/SIMD),
// phases split by CHANNEL halves in the same block; conv splits input
// channels with a padded-LDS partial combine. Also: skip exactly-zero
// bicubic taps in phase A (pn=16 weights are exactly (0,1,0,0) -> 4x less
// E-gather there; skipped terms contribute exactly +0 -> bit-identical).

#define BB 64
#define CC 32
#define HH 16
#define VV 4096
#define NTOT (BB*CC*HH*HH)   // 524288

__device__ __forceinline__ double cubicw(double x) {
    x = fabs(x);
    const double a = -0.75;
    if (x <= 1.0) return ((a + 2.0) * x - (a + 3.0)) * x * x + 1.0;
    if (x < 2.0)  return (((a * x - 5.0 * a) * x + 8.0 * a) * x - 4.0 * a);
    return 0.0;
}

// monotone float->uint map: d1<d2 (finite) => ordf(d1)<ordf(d2)
__device__ __forceinline__ unsigned int ordf(float d) {
    unsigned int b = __float_as_uint(d);
    return (b & 0x80000000u) ? ~b : (b | 0x80000000u);
}

// init: f_rest=f, f_hat=0, e2 rows, and z for scale 0 (pn=1: per-(b,c) mean).
__global__ void init_k(const float* __restrict__ f, const float* __restrict__ E,
                       float* __restrict__ f_rest, float* __restrict__ f_hat,
                       float* __restrict__ e2, float* __restrict__ z) {
    int i = blockIdx.x * 256 + threadIdx.x;
    if (i < NTOT) { f_rest[i] = f[i]; f_hat[i] = 0.f; }
    if (i < VV) {
        float s = 0.f;
        #pragma unroll
        for (int c = 0; c < CC; ++c) { float e = E[i * CC + c]; s += e * e; }
        e2[i] = s;
    }
    if (i < BB * CC) {
        const float* src = f + (size_t)i * (HH * HH);
        float s = 0.f;
        for (int j = 0; j < HH * HH; ++j) s += src[j];
        z[i] = s * (1.0f / 256.0f);
    }
}

// Small scales: grid (pn*pn, grp); block = 4 waves; each wave = same 64 points
// (one per lane), wave-specific code range (wave-uniform => scalar E loads).
__global__ __launch_bounds__(256, 4) void argsmall_k(const float* __restrict__ z,
        const float* __restrict__ E, const float* __restrict__ e2,
        unsigned long long* __restrict__ bestk, int M, int G, int gsz) {
    const int t = threadIdx.x;
    int m = blockIdx.x * 64 + (t & 63);
    int w = __builtin_amdgcn_readfirstlane(t >> 6);
    int wg = blockIdx.y * 4 + w;
    int v0 = wg * gsz;
    float zr[CC]; float z2 = 0.f;
    const float4* zp = (const float4*)(z + (size_t)m * CC);
    #pragma unroll
    for (int c4 = 0; c4 < 8; ++c4) {
        float4 v = zp[c4];
        zr[c4*4+0] = v.x; zr[c4*4+1] = v.y; zr[c4*4+2] = v.z; zr[c4*4+3] = v.w;
        z2 += v.x*v.x + v.y*v.y + v.z*v.z + v.w*v.w;
    }
    const float* e = E + (size_t)v0 * CC;
    float best = 3.4e38f; int bv = v0;
    for (int v = v0; v < v0 + gsz; v += 2, e += 2 * CC) {
        float a0 = 0.f, a1 = 0.f, b0 = 0.f, b1 = 0.f;
        #pragma unroll
        for (int c = 0; c < CC; c += 2) {
            a0 = fmaf(zr[c],   e[c],      a0);
            a1 = fmaf(zr[c+1], e[c+1],    a1);
            b0 = fmaf(zr[c],   e[CC+c],   b0);
            b1 = fmaf(zr[c+1], e[CC+c+1], b1);
        }
        float dA = fmaf(-2.f, a0 + a1, z2 + e2[v]);
        float dB = fmaf(-2.f, b0 + b1, z2 + e2[v+1]);
        if (dA < best) { best = dA; bv = v; }
        if (dB < best) { best = dB; bv = v + 1; }
    }
    bestk[(size_t)m * G + wg] = ((unsigned long long)ordf(best) << 32) |
                                (unsigned long long)(unsigned int)bv;
}

// Large scales (R12-proven): 2 points/thread; E tile + e2 staged in LDS; inner
// loop reads E via explicit float4 (ds_read_b128 broadcast). Keys [m][G].
__global__ __launch_bounds__(256, 4) void argbig_k(const float* __restrict__ z,
        const float* __restrict__ E, const float* __restrict__ e2,
        unsigned long long* __restrict__ bestk, int M, int G, int gsz) {
    __shared__ float s_e[128 * CC];
    __shared__ float s_e2[128];
    const int T = gridDim.x * 256;
    const int g = blockIdx.y;
    const int v0 = g * gsz;
    {
        const float4* src = (const float4*)(E + (size_t)v0 * CC);
        float4* dst = (float4*)s_e;
        for (int i = threadIdx.x; i < gsz * 8; i += 256) dst[i] = src[i];
        if (threadIdx.x < gsz) s_e2[threadIdx.x] = e2[v0 + threadIdx.x];
    }
    int   mm[2];
    bool  act[2];
    float zr[2][CC];
    float z2[2];
    #pragma unroll
    for (int pt = 0; pt < 2; ++pt) {
        int m0 = blockIdx.x * 256 + threadIdx.x + pt * T;
        act[pt] = (m0 < M);
        int m = act[pt] ? m0 : M - 1;
        mm[pt] = m;
        const float4* zp = (const float4*)(z + (size_t)m * CC);
        float zz = 0.f;
        #pragma unroll
        for (int c4 = 0; c4 < 8; ++c4) {
            float4 v = zp[c4];
            zr[pt][c4*4+0] = v.x; zr[pt][c4*4+1] = v.y;
            zr[pt][c4*4+2] = v.z; zr[pt][c4*4+3] = v.w;
            zz += v.x*v.x + v.y*v.y + v.z*v.z + v.w*v.w;
        }
        z2[pt] = zz;
    }
    __syncthreads();
    float best[2]; int bv[2];
    #pragma unroll
    for (int pt = 0; pt < 2; ++pt) { best[pt] = 3.4e38f; bv[pt] = v0; }
    const float4* ev = (const float4*)s_e;
    for (int vi = 0; vi < gsz; ++vi, ev += 8) {
        float4 e0 = ev[0], e1 = ev[1], e2v = ev[2], e3 = ev[3];
        float4 e4 = ev[4], e5 = ev[5], e6v = ev[6], e7 = ev[7];
        float ef[CC] = {e0.x,e0.y,e0.z,e0.w, e1.x,e1.y,e1.z,e1.w,
                        e2v.x,e2v.y,e2v.z,e2v.w, e3.x,e3.y,e3.z,e3.w,
                        e4.x,e4.y,e4.z,e4.w, e5.x,e5.y,e5.z,e5.w,
                        e6v.x,e6v.y,e6v.z,e6v.w, e7.x,e7.y,e7.z,e7.w};
        float a0 = 0.f, a1 = 0.f, b0 = 0.f, b1 = 0.f;
        #pragma unroll
        for (int c = 0; c < CC; c += 2) {
            a0 = fmaf(zr[0][c],   ef[c],   a0);
            a1 = fmaf(zr[0][c+1], ef[c+1], a1);
            b0 = fmaf(zr[1][c],   ef[c],   b0);
            b1 = fmaf(zr[1][c+1], ef[c+1], b1);
        }
        float e2c = s_e2[vi];
        float dA = fmaf(-2.f, a0 + a1, z2[0] + e2c);
        float dB = fmaf(-2.f, b0 + b1, z2[1] + e2c);
        int v = v0 + vi;
        if (dA < best[0]) { best[0] = dA; bv[0] = v; }
        if (dB < best[1]) { best[1] = dB; bv[1] = v; }
    }
    #pragma unroll
    for (int pt = 0; pt < 2; ++pt)
        if (act[pt])
            bestk[(size_t)mm[pt] * G + g] =
                ((unsigned long long)ordf(best[pt]) << 32) |
                (unsigned long long)(unsigned int)bv[pt];
}

// Fused (512 threads, 8 waves): group-reduce -> gather+bicubic with channel
// halves -> conv with ci halves + LDS partial combine -> update -> z_next.
__global__ __launch_bounds__(512) void fuse_k(const unsigned long long* __restrict__ bestk,
                      const float* __restrict__ E,
                      const float* __restrict__ pw, const float* __restrict__ pb,
                      float* __restrict__ f_hat, float* __restrict__ f_rest,
                      float* __restrict__ z_next,
                      int pn, int G, int TPP, int kphi, int pnn) {
    __shared__ float s_buf[CC * 18 * 20];
    __shared__ float s_pw[CC * 9 * 8];      // transposed: [ci*9+tap][col]
    __shared__ float s_part[256 * 9];       // conv partials, stride 9 (bank-safe)
    __shared__ int   s_idx[256];
    __shared__ float s_w[HH][4];
    __shared__ int   s_j[HH][4];
    __shared__ unsigned long long s_red[512];
    const int t   = threadIdx.x;
    const int cog = blockIdx.x;   // 0..3
    const int b   = blockIdx.y;   // 0..63
    const int P   = pn * pn;
    const int half = t >> 8;      // 0 or 1
    const int tl   = t & 255;

    // ---- phase 0: reduce over G keys per point (min d, tie -> min v) ----
    {
        int p = t / TPP, sub = t - p * TPP;
        unsigned long long bk = ~0ull;
        if (p < P) {
            const unsigned long long* kp = bestk + (size_t)(b * P + p) * G;
            for (int gg = sub; gg < G; gg += TPP) {
                unsigned long long o = kp[gg];
                if (o < bk) bk = o;
            }
        }
        s_red[t] = bk;
        __syncthreads();
        for (int s = TPP >> 1; s > 0; s >>= 1) {
            if ((sub < s) && p < P) {
                unsigned long long o = s_red[t + s];
                if (o < s_red[t]) s_red[t] = o;
            }
            __syncthreads();
        }
        if (t < P) s_idx[t] = (int)(unsigned int)(s_red[t * TPP] & 0xffffffffull);
    }
    if (t < HH) {
        double src = (t + 0.5) * (double)pn / 16.0 - 0.5;
        double fi = floor(src); int i0 = (int)fi; double tt = src - fi;
        #pragma unroll
        for (int k = 0; k < 4; ++k) {
            int j = i0 - 1 + k; j = j < 0 ? 0 : (j > pn - 1 ? pn - 1 : j);
            s_j[t][k] = j;
            s_w[t][k] = (float)cubicw((double)(k - 1) - tt);
        }
    }
    {
        const float* src = pw + ((size_t)(kphi * CC + cog * 8)) * CC * 9;
        for (int i = t; i < 8 * CC * 9; i += 512) {
            int col = i / (CC * 9);
            int r   = i - col * (CC * 9);
            s_pw[r * 8 + col] = src[i];
        }
    }
    __syncthreads();

    // ---- phase A: vertical bicubic + gather, channel half per thread ----
    if (tl < HH * pn) {
        int h = tl / pn, q = tl % pn;
        int cbase = half * 16;
        float acc[16];
        #pragma unroll
        for (int c = 0; c < 16; ++c) acc[c] = 0.f;
        #pragma unroll
        for (int k = 0; k < 4; ++k) {
            float wv = s_w[h][k];
            if (wv == 0.0f) continue;   // exact-zero tap: contributes exactly +0
            int row = s_idx[s_j[h][k] * pn + q];
            const float4* er = (const float4*)(E + (size_t)row * CC + cbase);
            #pragma unroll
            for (int c4 = 0; c4 < 4; ++c4) {
                float4 e4 = er[c4];
                acc[c4*4+0] = fmaf(wv, e4.x, acc[c4*4+0]);
                acc[c4*4+1] = fmaf(wv, e4.y, acc[c4*4+1]);
                acc[c4*4+2] = fmaf(wv, e4.z, acc[c4*4+2]);
                acc[c4*4+3] = fmaf(wv, e4.w, acc[c4*4+3]);
            }
        }
        #pragma unroll
        for (int c = 0; c < 16; ++c)
            s_buf[((cbase + c) * HH + h) * pn + q] = acc[c];
    }
    __syncthreads();

    // ---- phase B: horizontal bicubic -> padded hup, channel half ----
    {
        int h = tl >> 4, w = tl & 15;
        int cbase = half * 16;
        float acc[16];
        #pragma unroll
        for (int c = 0; c < 16; ++c) acc[c] = 0.f;
        #pragma unroll
        for (int k = 0; k < 4; ++k) {
            float wh = s_w[w][k];
            int j = s_j[w][k];
            #pragma unroll
            for (int c = 0; c < 16; ++c)
                acc[c] = fmaf(wh, s_buf[((cbase + c) * HH + h) * pn + j], acc[c]);
        }
        __syncthreads();   // all tmp reads done before aliased writes
        #pragma unroll
        for (int c = 0; c < 16; ++c)
            s_buf[((cbase + c) * 18 + h + 1) * 20 + w + 1] = acc[c];
        if (w == 0) {
            #pragma unroll
            for (int c = 0; c < 16; ++c) s_buf[((cbase + c) * 18 + h + 1) * 20] = 0.f;
        }
        if (w >= 13) {
            #pragma unroll
            for (int c = 0; c < 16; ++c) s_buf[((cbase + c) * 18 + h + 1) * 20 + w + 4] = 0.f;
        }
        if (h == 0) {
            #pragma unroll
            for (int c = 0; c < 16; ++c) {
                s_buf[((cbase + c) * 18) * 20 + w] = 0.f;
                if (w < 4) s_buf[((cbase + c) * 18) * 20 + 16 + w] = 0.f;
            }
        }
        if (h == 15) {
            #pragma unroll
            for (int c = 0; c < 16; ++c) {
                s_buf[((cbase + c) * 18 + 17) * 20 + w] = 0.f;
                if (w < 4) s_buf[((cbase + c) * 18 + 17) * 20 + 16 + w] = 0.f;
            }
        }
    }
    __syncthreads();

    // ---- conv 3x3: ci half per thread; partials combined via s_part ----
    int col = tl >> 5;                // 0..7 (wave-uniform pairs)
    int co  = cog * 8 + col;
    int s   = tl & 31;
    int h   = s >> 1;
    int w0  = (s & 1) * 8;
    float acc[8];
    float bias = pb[kphi * CC + co];
    #pragma unroll
    for (int o = 0; o < 8; ++o) acc[o] = (half == 0) ? bias : 0.f;
    int ci0 = half * 16;
    for (int ci = ci0; ci < ci0 + 16; ++ci) {
        const float* wb = &s_pw[(ci * 9) * 8 + col];
        #pragma unroll
        for (int kh = 0; kh < 3; ++kh) {
            const float4* xr = (const float4*)&s_buf[(ci * 18 + h + kh) * 20 + w0];
            float4 a0 = xr[0], a1 = xr[1], a2 = xr[2];
            float xf[12] = {a0.x, a0.y, a0.z, a0.w, a1.x, a1.y, a1.z, a1.w,
                            a2.x, a2.y, a2.z, a2.w};
            float k0 = wb[(kh*3+0)*8], k1 = wb[(kh*3+1)*8], k2 = wb[(kh*3+2)*8];
            #pragma unroll
            for (int o = 0; o < 8; ++o)
                acc[o] += xf[o] * k0 + xf[o+1] * k1 + xf[o+2] * k2;
        }
    }
    if (half == 1) {
        #pragma unroll
        for (int o = 0; o < 8; ++o) s_part[tl * 9 + o] = acc[o];
    }
    __syncthreads();

    // ---- epilogue (half 0 only): combine, update f_hat / f_rest ----
    float4 r0, r1;
    if (half == 0) {
        #pragma unroll
        for (int o = 0; o < 8; ++o) acc[o] += s_part[tl * 9 + o];
        size_t base = ((size_t)(b * CC + co) * HH + h) * HH + w0;
        float hf[8];
        #pragma unroll
        for (int o = 0; o < 8; ++o) {
            float hv = s_buf[(co * 18 + h + 1) * 20 + w0 + o + 1];
            hf[o] = 0.5f * hv + 0.5f * acc[o];
        }
        float4* fh = (float4*)(f_hat + base);
        float4* fr = (float4*)(f_rest + base);
        float4 v0 = fh[0], v1 = fh[1];
        v0.x += hf[0]; v0.y += hf[1]; v0.z += hf[2]; v0.w += hf[3];
        v1.x += hf[4]; v1.y += hf[5]; v1.z += hf[6]; v1.w += hf[7];
        fh[0] = v0; fh[1] = v1;
        r0 = fr[0]; r1 = fr[1];
        r0.x -= hf[0]; r0.y -= hf[1]; r0.z -= hf[2]; r0.w -= hf[3];
        r1.x -= hf[4]; r1.y -= hf[5]; r1.z -= hf[6]; r1.w -= hf[7];
        fr[0] = r0; fr[1] = r1;
    }

    // ---- emit next scale's z rows for this block's 8 channels ----
    if (pnn > 0) {
        __syncthreads();   // all s_buf reads (conv xr / hv) complete
        float* fn = s_buf; // reuse: fnew[col][16][16]
        if (half == 0) {
            float* d = &fn[(col * HH + h) * HH + w0];
            d[0] = r0.x; d[1] = r0.y; d[2] = r0.z; d[3] = r0.w;
            d[4] = r1.x; d[5] = r1.y; d[6] = r1.z; d[7] = r1.w;
        }
        __syncthreads();
        int P2 = pnn * pnn;
        for (int i = t; i < P2 * 8; i += 512) {
            int cl = i & 7, pq = i >> 3;
            int q2 = pq % pnn, p2 = pq / pnn;
            int sp = (p2 * HH) / pnn, ep = ((p2 + 1) * HH + pnn - 1) / pnn;
            int sq = (q2 * HH) / pnn, eq = ((q2 + 1) * HH + pnn - 1) / pnn;
            float wgt = 1.0f / ((float)(ep - sp) * (float)(eq - sq));
            float sum = 0.f;
            for (int h2 = sp; h2 < ep; ++h2)
                for (int w2 = sq; w2 < eq; ++w2)
                    sum += fn[(cl * HH + h2) * HH + w2];
            z_next[((size_t)(b * P2 + pq)) * CC + cog * 8 + cl] = sum * wgt;
        }
    }
}

extern "C" void kernel_launch(void* const* d_in, const int* in_sizes, int n_in,
                              void* d_out, int out_size, void* d_ws, size_t ws_size,
                              hipStream_t stream) {
    const float* f  = (const float*)d_in[0];
    const float* E  = (const float*)d_in[1];
    const float* pw = (const float*)d_in[2];
    const float* pb = (const float*)d_in[3];
    float* out = (float*)d_out;

    float* wsf    = (float*)d_ws;
    float* f_rest = wsf;
    float* e2     = wsf + (size_t)NTOT;
    unsigned long long* bestk = (unsigned long long*)(e2 + VV);  // 524288 u64
    float* z      = (float*)(bestk + 524288);

    int phik[10];
    {
        double start = 1.0 / 3.0 / 4.0;
        double stop  = 1.0 - 1.0 / 3.0 / 4.0;
        double step  = (stop - start) / 3.0;
        double ticks[4];
        for (int i = 0; i < 4; ++i) ticks[i] = (double)i * step + start;
        ticks[3] = stop;
        for (int si = 0; si < 10; ++si) {
            double s = (double)si / 9.0;
            int bk = 0; double bd = fabs(ticks[0] - s);
            for (int tq = 1; tq < 4; ++tq) {
                double d2 = fabs(ticks[tq] - s);
                if (d2 < bd) { bd = d2; bk = tq; }
            }
            phik[si] = bk;
        }
    }

    static const int pns[10]  = {1, 2, 3, 4, 5, 6, 8, 10, 13, 16};
    static const int grpS[10] = {256, 128, 64, 32, 32, 16, 0, 0, 0, 0};
    static const int grpB[10] = {0, 0, 0, 0, 0, 0, 128, 64, 32, 32};

    init_k<<<(NTOT + 255) / 256, 256, 0, stream>>>(f, E, f_rest, out, e2, z);

    for (int si = 0; si < 10; ++si) {
        int pn = pns[si];
        int P = pn * pn;
        int M = BB * P;
        int G, TPP;
        if (pn <= 6) {
            int grp = grpS[si];
            G = grp * 4;
            int gsz = VV / G;
            argsmall_k<<<dim3(P, grp), 256, 0, stream>>>(z, E, e2, bestk, M, G, gsz);
        } else {
            G = grpB[si];
            int gsz = VV / G;
            int bx = (M + 511) / 512;
            dim3 ag(bx, G);
            argbig_k<<<ag, 256, 0, stream>>>(z, E, e2, bestk, M, G, gsz);
        }
        // TPP for the 512-thread fuse: largest pow2 with TPP*2*P <= 512
        TPP = 1;
        while (TPP * 2 * P <= 512) TPP *= 2;
        int pnn = (si < 9) ? pns[si + 1] : 0;
        fuse_k<<<dim3(4, BB), 512, 0, stream>>>(bestk, E, pw, pb,
                                                out, f_rest, z,
                                                pn, G, TPP, phik[si], pnn);
    }
}

// Round 17
// 467.474 us; speedup vs baseline: 1.4059x; 1.1090x over previous
//
#include <hip/hip_runtime.h>
#include <cmath>

// Multi-scale residual VQ, round 17 = R16 + MFMA argmin for big scales.
// fp32 VALU argmin hit its structural wall (63% of 157 TF). Path past it:
// 3-way bf16-split MFMA emulation (6x mfma_f32_16x16x32_bf16 per tile,
// error ~1e-6 rel, comparable to the passing fp32 chain). E splits
// precomputed in init (ws +786KB); z splits built in-register per tile.
// ws-branched fallback to R15's proven argbig if workspace is short.

#define BB 64
#define CC 32
#define HH 16
#define VV 4096
#define NTOT (BB*CC*HH*HH)   // 524288

typedef __attribute__((ext_vector_type(8))) short bf16x8;
typedef __attribute__((ext_vector_type(4))) float f32x4;

__device__ __forceinline__ double cubicw(double x) {
    x = fabs(x);
    const double a = -0.75;
    if (x <= 1.0) return ((a + 2.0) * x - (a + 3.0)) * x * x + 1.0;
    if (x < 2.0)  return (((a * x - 5.0 * a) * x + 8.0 * a) * x - 4.0 * a);
    return 0.0;
}

__device__ __forceinline__ unsigned int ordf(float d) {
    unsigned int b = __float_as_uint(d);
    return (b & 0x80000000u) ? ~b : (b | 0x80000000u);
}

__device__ __forceinline__ short f2bf(float x) {   // RNE float->bf16
    unsigned u = __float_as_uint(x);
    unsigned r = (u + 0x7fffu + ((u >> 16) & 1u)) >> 16;
    return (short)r;
}
__device__ __forceinline__ float bf2f(short h) {
    return __uint_as_float(((unsigned)(unsigned short)h) << 16);
}

// init: f_rest=f, f_hat=0, e2 rows, z for scale 0, and (if es) E bf16 splits.
__global__ void init_k(const float* __restrict__ f, const float* __restrict__ E,
                       float* __restrict__ f_rest, float* __restrict__ f_hat,
                       float* __restrict__ e2, float* __restrict__ z,
                       float* __restrict__ es) {
    int i = blockIdx.x * 256 + threadIdx.x;
    if (i < NTOT) { f_rest[i] = f[i]; f_hat[i] = 0.f; }
    if (i < VV) {
        float s = 0.f;
        unsigned short* ew = es ? (unsigned short*)(es + (size_t)i * 48) : (unsigned short*)0;
        #pragma unroll
        for (int c = 0; c < CC; ++c) {
            float x = E[i * CC + c];
            s += x * x;
            if (ew) {
                short h = f2bf(x); float rm = x - bf2f(h);
                short m = f2bf(rm); float rl = rm - bf2f(m);
                short l = f2bf(rl);
                ew[c] = (unsigned short)h;
                ew[32 + c] = (unsigned short)m;
                ew[64 + c] = (unsigned short)l;
            }
        }
        e2[i] = s;
    }
    if (i < BB * CC) {
        const float* src = f + (size_t)i * (HH * HH);
        float s = 0.f;
        for (int j = 0; j < HH * HH; ++j) s += src[j];
        z[i] = s * (1.0f / 256.0f);
    }
}

// Small scales: grid (pn*pn, grp); block = 4 waves; each wave = same 64 points
// (one per lane), wave-specific code range (wave-uniform => scalar E loads).
__global__ __launch_bounds__(256, 4) void argsmall_k(const float* __restrict__ z,
        const float* __restrict__ E, const float* __restrict__ e2,
        unsigned long long* __restrict__ bestk, int M, int G, int gsz) {
    const int t = threadIdx.x;
    int m = blockIdx.x * 64 + (t & 63);
    int w = __builtin_amdgcn_readfirstlane(t >> 6);
    int wg = blockIdx.y * 4 + w;
    int v0 = wg * gsz;
    float zr[CC]; float z2 = 0.f;
    const float4* zp = (const float4*)(z + (size_t)m * CC);
    #pragma unroll
    for (int c4 = 0; c4 < 8; ++c4) {
        float4 v = zp[c4];
        zr[c4*4+0] = v.x; zr[c4*4+1] = v.y; zr[c4*4+2] = v.z; zr[c4*4+3] = v.w;
        z2 += v.x*v.x + v.y*v.y + v.z*v.z + v.w*v.w;
    }
    const float* e = E + (size_t)v0 * CC;
    float best = 3.4e38f; int bv = v0;
    for (int v = v0; v < v0 + gsz; v += 2, e += 2 * CC) {
        float a0 = 0.f, a1 = 0.f, b0 = 0.f, b1 = 0.f;
        #pragma unroll
        for (int c = 0; c < CC; c += 2) {
            a0 = fmaf(zr[c],   e[c],      a0);
            a1 = fmaf(zr[c+1], e[c+1],    a1);
            b0 = fmaf(zr[c],   e[CC+c],   b0);
            b1 = fmaf(zr[c+1], e[CC+c+1], b1);
        }
        float dA = fmaf(-2.f, a0 + a1, z2 + e2[v]);
        float dB = fmaf(-2.f, b0 + b1, z2 + e2[v+1]);
        if (dA < best) { best = dA; bv = v; }
        if (dB < best) { best = dB; bv = v + 1; }
    }
    bestk[(size_t)m * G + wg] = ((unsigned long long)ordf(best) << 32) |
                                (unsigned long long)(unsigned int)bv;
}

// MFMA argmin (big scales): wave = 2x 16-point tiles; 6x bf16-split MFMA per
// (tile, 16-code tile); packed-u64 butterfly reduce; keys [m][G].
__global__ __launch_bounds__(256, 4) void argmf_k(const float* __restrict__ z,
        const float* __restrict__ es, const float* __restrict__ e2,
        unsigned long long* __restrict__ bestk, int M, int G, int gsz) {
    __shared__ float s_es[128 * 52];   // 52-word stride: bank-safe, 16B-aligned
    __shared__ float s_e2[128];
    const int t = threadIdx.x;
    const int g = blockIdx.y;
    const int v0 = g * gsz;
    for (int i = t; i < gsz * 12; i += 256) {
        int row = i / 12, part = i - row * 12;
        *(float4*)&s_es[row * 52 + part * 4] =
            *(const float4*)&es[(size_t)(v0 + row) * 48 + part * 4];
    }
    for (int i = t; i < gsz; i += 256) s_e2[i] = e2[v0 + i];

    const int lane = t & 63;
    const int w = t >> 6;
    const int n = lane & 15, kq = lane >> 4;

    int tb[2]; bf16x8 ah[2], am[2], al[2]; float z2r[2][4];
    #pragma unroll
    for (int pt = 0; pt < 2; ++pt) {
        int tb0 = blockIdx.x * 128 + w * 32 + pt * 16;
        if (tb0 > M - 16) tb0 = M - 16;   // tail: duplicate identical work/keys
        tb[pt] = tb0;
        const float* zp = z + (size_t)(tb0 + n) * CC + kq * 8;
        float4 zA = *(const float4*)zp, zB = *(const float4*)(zp + 4);
        float zv[8] = {zA.x, zA.y, zA.z, zA.w, zB.x, zB.y, zB.z, zB.w};
        float p2 = 0.f;
        #pragma unroll
        for (int j = 0; j < 8; ++j) {
            float x = zv[j];
            p2 = fmaf(x, x, p2);
            short h = f2bf(x); float rm = x - bf2f(h);
            short m = f2bf(rm); float rl = rm - bf2f(m);
            short l = f2bf(rl);
            ah[pt][j] = h; am[pt][j] = m; al[pt][j] = l;
        }
        p2 += __shfl_xor(p2, 16);   // sum partials across the 4 quads
        p2 += __shfl_xor(p2, 32);   // now p2 = z2 of row n (all lanes)
        #pragma unroll
        for (int r = 0; r < 4; ++r)
            z2r[pt][r] = __shfl(p2, kq * 4 + r);   // z2 of this lane's C rows
    }
    __syncthreads();

    float bd[2][4]; int bc[2][4];
    #pragma unroll
    for (int pt = 0; pt < 2; ++pt)
        #pragma unroll
        for (int r = 0; r < 4; ++r) { bd[pt][r] = 3.4e38f; bc[pt][r] = 0; }

    const int nct = gsz >> 4;
    for (int ct = 0; ct < nct; ++ct) {
        int base = (ct * 16 + n) * 52 + kq * 4;
        bf16x8 eh = *(const bf16x8*)&s_es[base];
        bf16x8 em = *(const bf16x8*)&s_es[base + 16];
        bf16x8 el = *(const bf16x8*)&s_es[base + 32];
        float e2c = s_e2[ct * 16 + n];
        #pragma unroll
        for (int pt = 0; pt < 2; ++pt) {
            f32x4 C = {0.f, 0.f, 0.f, 0.f};
            C = __builtin_amdgcn_mfma_f32_16x16x32_bf16(ah[pt], eh, C, 0, 0, 0);
            C = __builtin_amdgcn_mfma_f32_16x16x32_bf16(ah[pt], em, C, 0, 0, 0);
            C = __builtin_amdgcn_mfma_f32_16x16x32_bf16(am[pt], eh, C, 0, 0, 0);
            C = __builtin_amdgcn_mfma_f32_16x16x32_bf16(ah[pt], el, C, 0, 0, 0);
            C = __builtin_amdgcn_mfma_f32_16x16x32_bf16(al[pt], eh, C, 0, 0, 0);
            C = __builtin_amdgcn_mfma_f32_16x16x32_bf16(am[pt], em, C, 0, 0, 0);
            #pragma unroll
            for (int r = 0; r < 4; ++r) {
                float d = fmaf(-2.f, C[r], z2r[pt][r] + e2c);
                if (d < bd[pt][r]) { bd[pt][r] = d; bc[pt][r] = ct; }
            }
        }
    }
    #pragma unroll
    for (int pt = 0; pt < 2; ++pt) {
        #pragma unroll
        for (int r = 0; r < 4; ++r) {
            int v = v0 + bc[pt][r] * 16 + n;
            unsigned long long k = ((unsigned long long)ordf(bd[pt][r]) << 32) |
                                   (unsigned long long)(unsigned int)v;
            #pragma unroll
            for (int msk = 1; msk < 16; msk <<= 1) {
                unsigned long long o = __shfl_xor(k, msk);
                if (o < k) k = o;
            }
            if (n == 0)
                bestk[(size_t)(tb[pt] + kq * 4 + r) * G + g] = k;
        }
    }
}

// Fallback big-scale argmin (R12/R15-proven): LDS E tile, float4 reads.
__global__ __launch_bounds__(256, 4) void argbig_k(const float* __restrict__ z,
        const float* __restrict__ E, const float* __restrict__ e2,
        unsigned long long* __restrict__ bestk, int M, int G, int gsz) {
    __shared__ float s_e[128 * CC];
    __shared__ float s_e2[128];
    const int T = gridDim.x * 256;
    const int g = blockIdx.y;
    const int v0 = g * gsz;
    {
        const float4* src = (const float4*)(E + (size_t)v0 * CC);
        float4* dst = (float4*)s_e;
        for (int i = threadIdx.x; i < gsz * 8; i += 256) dst[i] = src[i];
        if (threadIdx.x < gsz) s_e2[threadIdx.x] = e2[v0 + threadIdx.x];
    }
    int   mm[2];
    bool  act[2];
    float zr[2][CC];
    float z2[2];
    #pragma unroll
    for (int pt = 0; pt < 2; ++pt) {
        int m0 = blockIdx.x * 256 + threadIdx.x + pt * T;
        act[pt] = (m0 < M);
        int m = act[pt] ? m0 : M - 1;
        mm[pt] = m;
        const float4* zp = (const float4*)(z + (size_t)m * CC);
        float zz = 0.f;
        #pragma unroll
        for (int c4 = 0; c4 < 8; ++c4) {
            float4 v = zp[c4];
            zr[pt][c4*4+0] = v.x; zr[pt][c4*4+1] = v.y;
            zr[pt][c4*4+2] = v.z; zr[pt][c4*4+3] = v.w;
            zz += v.x*v.x + v.y*v.y + v.z*v.z + v.w*v.w;
        }
        z2[pt] = zz;
    }
    __syncthreads();
    float best[2]; int bv[2];
    #pragma unroll
    for (int pt = 0; pt < 2; ++pt) { best[pt] = 3.4e38f; bv[pt] = v0; }
    const float4* ev = (const float4*)s_e;
    for (int vi = 0; vi < gsz; ++vi, ev += 8) {
        float4 e0 = ev[0], e1 = ev[1], e2v = ev[2], e3 = ev[3];
        float4 e4 = ev[4], e5 = ev[5], e6v = ev[6], e7 = ev[7];
        float ef[CC] = {e0.x,e0.y,e0.z,e0.w, e1.x,e1.y,e1.z,e1.w,
                        e2v.x,e2v.y,e2v.z,e2v.w, e3.x,e3.y,e3.z,e3.w,
                        e4.x,e4.y,e4.z,e4.w, e5.x,e5.y,e5.z,e5.w,
                        e6v.x,e6v.y,e6v.z,e6v.w, e7.x,e7.y,e7.z,e7.w};
        float a0 = 0.f, a1 = 0.f, b0 = 0.f, b1 = 0.f;
        #pragma unroll
        for (int c = 0; c < CC; c += 2) {
            a0 = fmaf(zr[0][c],   ef[c],   a0);
            a1 = fmaf(zr[0][c+1], ef[c+1], a1);
            b0 = fmaf(zr[1][c],   ef[c],   b0);
            b1 = fmaf(zr[1][c+1], ef[c+1], b1);
        }
        float e2c = s_e2[vi];
        float dA = fmaf(-2.f, a0 + a1, z2[0] + e2c);
        float dB = fmaf(-2.f, b0 + b1, z2[1] + e2c);
        int v = v0 + vi;
        if (dA < best[0]) { best[0] = dA; bv[0] = v; }
        if (dB < best[1]) { best[1] = dB; bv[1] = v; }
    }
    #pragma unroll
    for (int pt = 0; pt < 2; ++pt)
        if (act[pt])
            bestk[(size_t)mm[pt] * G + g] =
                ((unsigned long long)ordf(best[pt]) << 32) |
                (unsigned long long)(unsigned int)bv[pt];
}

// Fused (512 threads, 8 waves) — unchanged from R16 (passing).
__global__ __launch_bounds__(512) void fuse_k(const unsigned long long* __restrict__ bestk,
                      const float* __restrict__ E,
                      const float* __restrict__ pw, const float* __restrict__ pb,
                      float* __restrict__ f_hat, float* __restrict__ f_rest,
                      float* __restrict__ z_next,
                      int pn, int G, int TPP, int kphi, int pnn) {
    __shared__ float s_buf[CC * 18 * 20];
    __shared__ float s_pw[CC * 9 * 8];
    __shared__ float s_part[256 * 9];
    __shared__ int   s_idx[256];
    __shared__ float s_w[HH][4];
    __shared__ int   s_j[HH][4];
    __shared__ unsigned long long s_red[512];
    const int t   = threadIdx.x;
    const int cog = blockIdx.x;
    const int b   = blockIdx.y;
    const int P   = pn * pn;
    const int half = t >> 8;
    const int tl   = t & 255;

    {
        int p = t / TPP, sub = t - p * TPP;
        unsigned long long bk = ~0ull;
        if (p < P) {
            const unsigned long long* kp = bestk + (size_t)(b * P + p) * G;
            for (int gg = sub; gg < G; gg += TPP) {
                unsigned long long o = kp[gg];
                if (o < bk) bk = o;
            }
        }
        s_red[t] = bk;
        __syncthreads();
        for (int s = TPP >> 1; s > 0; s >>= 1) {
            if ((sub < s) && p < P) {
                unsigned long long o = s_red[t + s];
                if (o < s_red[t]) s_red[t] = o;
            }
            __syncthreads();
        }
        if (t < P) s_idx[t] = (int)(unsigned int)(s_red[t * TPP] & 0xffffffffull);
    }
    if (t < HH) {
        double src = (t + 0.5) * (double)pn / 16.0 - 0.5;
        double fi = floor(src); int i0 = (int)fi; double tt = src - fi;
        #pragma unroll
        for (int k = 0; k < 4; ++k) {
            int j = i0 - 1 + k; j = j < 0 ? 0 : (j > pn - 1 ? pn - 1 : j);
            s_j[t][k] = j;
            s_w[t][k] = (float)cubicw((double)(k - 1) - tt);
        }
    }
    {
        const float* src = pw + ((size_t)(kphi * CC + cog * 8)) * CC * 9;
        for (int i = t; i < 8 * CC * 9; i += 512) {
            int col = i / (CC * 9);
            int r   = i - col * (CC * 9);
            s_pw[r * 8 + col] = src[i];
        }
    }
    __syncthreads();

    if (tl < HH * pn) {
        int h = tl / pn, q = tl % pn;
        int cbase = half * 16;
        float acc[16];
        #pragma unroll
        for (int c = 0; c < 16; ++c) acc[c] = 0.f;
        #pragma unroll
        for (int k = 0; k < 4; ++k) {
            float wv = s_w[h][k];
            if (wv == 0.0f) continue;
            int row = s_idx[s_j[h][k] * pn + q];
            const float4* er = (const float4*)(E + (size_t)row * CC + cbase);
            #pragma unroll
            for (int c4 = 0; c4 < 4; ++c4) {
                float4 e4 = er[c4];
                acc[c4*4+0] = fmaf(wv, e4.x, acc[c4*4+0]);
                acc[c4*4+1] = fmaf(wv, e4.y, acc[c4*4+1]);
                acc[c4*4+2] = fmaf(wv, e4.z, acc[c4*4+2]);
                acc[c4*4+3] = fmaf(wv, e4.w, acc[c4*4+3]);
            }
        }
        #pragma unroll
        for (int c = 0; c < 16; ++c)
            s_buf[((cbase + c) * HH + h) * pn + q] = acc[c];
    }
    __syncthreads();

    {
        int h = tl >> 4, w = tl & 15;
        int cbase = half * 16;
        float acc[16];
        #pragma unroll
        for (int c = 0; c < 16; ++c) acc[c] = 0.f;
        #pragma unroll
        for (int k = 0; k < 4; ++k) {
            float wh = s_w[w][k];
            int j = s_j[w][k];
            #pragma unroll
            for (int c = 0; c < 16; ++c)
                acc[c] = fmaf(wh, s_buf[((cbase + c) * HH + h) * pn + j], acc[c]);
        }
        __syncthreads();
        #pragma unroll
        for (int c = 0; c < 16; ++c)
            s_buf[((cbase + c) * 18 + h + 1) * 20 + w + 1] = acc[c];
        if (w == 0) {
            #pragma unroll
            for (int c = 0; c < 16; ++c) s_buf[((cbase + c) * 18 + h + 1) * 20] = 0.f;
        }
        if (w >= 13) {
            #pragma unroll
            for (int c = 0; c < 16; ++c) s_buf[((cbase + c) * 18 + h + 1) * 20 + w + 4] = 0.f;
        }
        if (h == 0) {
            #pragma unroll
            for (int c = 0; c < 16; ++c) {
                s_buf[((cbase + c) * 18) * 20 + w] = 0.f;
                if (w < 4) s_buf[((cbase + c) * 18) * 20 + 16 + w] = 0.f;
            }
        }
        if (h == 15) {
            #pragma unroll
            for (int c = 0; c < 16; ++c) {
                s_buf[((cbase + c) * 18 + 17) * 20 + w] = 0.f;
                if (w < 4) s_buf[((cbase + c) * 18 + 17) * 20 + 16 + w] = 0.f;
            }
        }
    }
    __syncthreads();

    int col = tl >> 5;
    int co  = cog * 8 + col;
    int s   = tl & 31;
    int h   = s >> 1;
    int w0  = (s & 1) * 8;
    float acc[8];
    float bias = pb[kphi * CC + co];
    #pragma unroll
    for (int o = 0; o < 8; ++o) acc[o] = (half == 0) ? bias : 0.f;
    int ci0 = half * 16;
    for (int ci = ci0; ci < ci0 + 16; ++ci) {
        const float* wb = &s_pw[(ci * 9) * 8 + col];
        #pragma unroll
        for (int kh = 0; kh < 3; ++kh) {
            const float4* xr = (const float4*)&s_buf[(ci * 18 + h + kh) * 20 + w0];
            float4 a0 = xr[0], a1 = xr[1], a2 = xr[2];
            float xf[12] = {a0.x, a0.y, a0.z, a0.w, a1.x, a1.y, a1.z, a1.w,
                            a2.x, a2.y, a2.z, a2.w};
            float k0 = wb[(kh*3+0)*8], k1 = wb[(kh*3+1)*8], k2 = wb[(kh*3+2)*8];
            #pragma unroll
            for (int o = 0; o < 8; ++o)
                acc[o] += xf[o] * k0 + xf[o+1] * k1 + xf[o+2] * k2;
        }
    }
    if (half == 1) {
        #pragma unroll
        for (int o = 0; o < 8; ++o) s_part[tl * 9 + o] = acc[o];
    }
    __syncthreads();

    float4 r0, r1;
    if (half == 0) {
        #pragma unroll
        for (int o = 0; o < 8; ++o) acc[o] += s_part[tl * 9 + o];
        size_t base = ((size_t)(b * CC + co) * HH + h) * HH + w0;
        float hf[8];
        #pragma unroll
        for (int o = 0; o < 8; ++o) {
            float hv = s_buf[(co * 18 + h + 1) * 20 + w0 + o + 1];
            hf[o] = 0.5f * hv + 0.5f * acc[o];
        }
        float4* fh = (float4*)(f_hat + base);
        float4* fr = (float4*)(f_rest + base);
        float4 v0 = fh[0], v1 = fh[1];
        v0.x += hf[0]; v0.y += hf[1]; v0.z += hf[2]; v0.w += hf[3];
        v1.x += hf[4]; v1.y += hf[5]; v1.z += hf[6]; v1.w += hf[7];
        fh[0] = v0; fh[1] = v1;
        r0 = fr[0]; r1 = fr[1];
        r0.x -= hf[0]; r0.y -= hf[1]; r0.z -= hf[2]; r0.w -= hf[3];
        r1.x -= hf[4]; r1.y -= hf[5]; r1.z -= hf[6]; r1.w -= hf[7];
        fr[0] = r0; fr[1] = r1;
    }

    if (pnn > 0) {
        __syncthreads();
        float* fn = s_buf;
        if (half == 0) {
            float* d = &fn[(col * HH + h) * HH + w0];
            d[0] = r0.x; d[1] = r0.y; d[2] = r0.z; d[3] = r0.w;
            d[4] = r1.x; d[5] = r1.y; d[6] = r1.z; d[7] = r1.w;
        }
        __syncthreads();
        int P2 = pnn * pnn;
        for (int i = t; i < P2 * 8; i += 512) {
            int cl = i & 7, pq = i >> 3;
            int q2 = pq % pnn, p2 = pq / pnn;
            int sp = (p2 * HH) / pnn, ep = ((p2 + 1) * HH + pnn - 1) / pnn;
            int sq = (q2 * HH) / pnn, eq = ((q2 + 1) * HH + pnn - 1) / pnn;
            float wgt = 1.0f / ((float)(ep - sp) * (float)(eq - sq));
            float sum = 0.f;
            for (int h2 = sp; h2 < ep; ++h2)
                for (int w2 = sq; w2 < eq; ++w2)
                    sum += fn[(cl * HH + h2) * HH + w2];
            z_next[((size_t)(b * P2 + pq)) * CC + cog * 8 + cl] = sum * wgt;
        }
    }
}

extern "C" void kernel_launch(void* const* d_in, const int* in_sizes, int n_in,
                              void* d_out, int out_size, void* d_ws, size_t ws_size,
                              hipStream_t stream) {
    const float* f  = (const float*)d_in[0];
    const float* E  = (const float*)d_in[1];
    const float* pw = (const float*)d_in[2];
    const float* pb = (const float*)d_in[3];
    float* out = (float*)d_out;

    // ws: f_rest | e2 | bestk(4MB) | z(2MB) | es(786KB, MFMA path only)
    const size_t need_mf = (size_t)(NTOT + VV) * 4 + (size_t)524288 * 8 +
                           (size_t)524288 * 4 + (size_t)VV * 48 * 4;
    const bool use_mf = (ws_size >= need_mf);

    float* wsf    = (float*)d_ws;
    float* f_rest = wsf;
    float* e2     = wsf + (size_t)NTOT;
    unsigned long long* bestk = (unsigned long long*)(e2 + VV);
    float* z      = (float*)(bestk + 524288);
    float* es     = use_mf ? (z + 524288) : (float*)0;

    int phik[10];
    {
        double start = 1.0 / 3.0 / 4.0;
        double stop  = 1.0 - 1.0 / 3.0 / 4.0;
        double step  = (stop - start) / 3.0;
        double ticks[4];
        for (int i = 0; i < 4; ++i) ticks[i] = (double)i * step + start;
        ticks[3] = stop;
        for (int si = 0; si < 10; ++si) {
            double s = (double)si / 9.0;
            int bk = 0; double bd = fabs(ticks[0] - s);
            for (int tq = 1; tq < 4; ++tq) {
                double d2 = fabs(ticks[tq] - s);
                if (d2 < bd) { bd = d2; bk = tq; }
            }
            phik[si] = bk;
        }
    }

    static const int pns[10]  = {1, 2, 3, 4, 5, 6, 8, 10, 13, 16};
    static const int grpS[10] = {256, 128, 64, 32, 32, 16, 0, 0, 0, 0};
    static const int grpF[10] = {0, 0, 0, 0, 0, 0, 128, 64, 32, 32};  // fallback
    static const int grpM[10] = {0, 0, 0, 0, 0, 0, 64, 64, 32, 32};   // MFMA path

    init_k<<<(NTOT + 255) / 256, 256, 0, stream>>>(f, E, f_rest, out, e2, z, es);

    for (int si = 0; si < 10; ++si) {
        int pn = pns[si];
        int P = pn * pn;
        int M = BB * P;
        int G, TPP;
        if (pn <= 6) {
            int grp = grpS[si];
            G = grp * 4;
            int gsz = VV / G;
            argsmall_k<<<dim3(P, grp), 256, 0, stream>>>(z, E, e2, bestk, M, G, gsz);
        } else if (use_mf) {
            G = grpM[si];
            int gsz = VV / G;
            int bx = (M + 127) / 128;
            argmf_k<<<dim3(bx, G), 256, 0, stream>>>(z, es, e2, bestk, M, G, gsz);
        } else {
            G = grpF[si];
            int gsz = VV / G;
            int bx = (M + 511) / 512;
            argbig_k<<<dim3(bx, G), 256, 0, stream>>>(z, E, e2, bestk, M, G, gsz);
        }
        TPP = 1;
        while (TPP * 2 * P <= 512) TPP *= 2;
        int pnn = (si < 9) ? pns[si + 1] : 0;
        fuse_k<<<dim3(4, BB), 512, 0, stream>>>(bestk, E, pw, pb,
                                                out, f_rest, z,
                                                pn, G, TPP, phik[si], pnn);
    }
}